// Round 18
// baseline (149.505 us; speedup 1.0000x reference)
//
#include <hip/hip_runtime.h>

#define QLEN 512
#define MLEN 512
#define KLEN 1024
#define BB   8
#define DMODEL 1024
#define NH   16
#define HD   64
#define NF   384
#define ATT_SCALE 0.125f
#define EPSV 1e-5f

typedef float v4f __attribute__((ext_vector_type(4)));
typedef float f32x16 __attribute__((ext_vector_type(16)));
typedef short bf16x8 __attribute__((ext_vector_type(8)));
typedef long lx2 __attribute__((ext_vector_type(2)));
typedef unsigned int u32x4 __attribute__((ext_vector_type(4)));
typedef unsigned int u32x2 __attribute__((ext_vector_type(2)));
typedef unsigned short u16x8 __attribute__((ext_vector_type(8)));

__device__ __forceinline__ unsigned short f2bf(float f) {
    unsigned int x = __builtin_bit_cast(unsigned int, f);
    x += 0x7fffu + ((x >> 16) & 1u);
    return (unsigned short)(x >> 16);
}

__device__ __forceinline__ void gll16(const void* g, void* l) {
    __builtin_amdgcn_global_load_lds(
        (const __attribute__((address_space(1))) unsigned int*)g,
        (__attribute__((address_space(3))) unsigned int*)l, 16, 0, 0);
}

// fp8 feature layout (bytes): feat[bh][rb][cell:24][row:64][16 fp8]
// fp8 GEMM row layout (1024 fp8/row), granule-permuted per 128-byte K-step:
//   k = kstep*128 + kk*32 + lg*8 + e  <->  byte = kstep*128 + (lg*2+(kk>>1))*16 + (kk&1)*8 + e

// ---------------------------------------------------------------------------
// Merged converts: blocks [0,5632) = fp8 (c rows, Wkv x32, Wq x32);
// blocks [5632,6656) = Wo -> bf16.
// ---------------------------------------------------------------------------
__global__ __launch_bounds__(256)
void cvt_kernel(const float* __restrict__ h, const float* __restrict__ mems,
                const float* __restrict__ Wkv, const float* __restrict__ Wq,
                const float* __restrict__ Wo,
                unsigned char* __restrict__ c8, unsigned char* __restrict__ wkv8,
                unsigned char* __restrict__ wq8, unsigned short* __restrict__ wob)
{
    int blk = blockIdx.x;
    if (blk >= 5632) {
        int i = ((blk - 5632) * 256 + threadIdx.x) * 4;
        v4f v = *(const v4f*)(Wo + i);
        unsigned int p0, p1;
        asm("v_cvt_pk_bf16_f32 %0, %1, %2" : "=v"(p0) : "v"(v[0]), "v"(v[1]));
        asm("v_cvt_pk_bf16_f32 %0, %1, %2" : "=v"(p1) : "v"(v[2]), "v"(v[3]));
        uint2 u; u.x = p0; u.y = p1;
        *(uint2*)(wob + i) = u;
        return;
    }
    int tid = blk * 256 + threadIdx.x;
    const float* src; unsigned char* dstrow; float scale; int row, k0;
    if (tid < 1048576) {               // c: 8192 rows
        int base = tid * 8; row = base >> 10; k0 = base & 1023;
        src = (row < 4096) ? (mems + (size_t)row * 1024)
                           : (h + (size_t)(row - 4096) * 1024);
        dstrow = c8 + (size_t)row * 1024; scale = 1.f;
    } else if (tid < 1310720) {        // Wkv: 2048 rows, x32
        int t2 = tid - 1048576; int base = t2 * 8; row = base >> 10; k0 = base & 1023;
        src = Wkv + (size_t)row * 1024; dstrow = wkv8 + (size_t)row * 1024; scale = 32.f;
    } else {                           // Wq: 1024 rows, x32
        int t2 = tid - 1310720; int base = t2 * 8; row = base >> 10; k0 = base & 1023;
        src = Wq + (size_t)row * 1024; dstrow = wq8 + (size_t)row * 1024; scale = 32.f;
    }
    v4f a = *(const v4f*)(src + k0);
    v4f b = *(const v4f*)(src + k0 + 4);
    int v0 = __builtin_amdgcn_cvt_pk_fp8_f32(a[0]*scale, a[1]*scale, 0, false);
    v0     = __builtin_amdgcn_cvt_pk_fp8_f32(a[2]*scale, a[3]*scale, v0, true);
    int v1 = __builtin_amdgcn_cvt_pk_fp8_f32(b[0]*scale, b[1]*scale, 0, false);
    v1     = __builtin_amdgcn_cvt_pk_fp8_f32(b[2]*scale, b[3]*scale, v1, true);
    int kk = (k0 & 127) >> 5;
    int lg = (k0 & 31) >> 3;
    uint2 st; st.x = (unsigned int)v0; st.y = (unsigned int)v1;
    *(uint2*)(dstrow + (k0 & ~127) + (lg * 2 + (kk >> 1)) * 16 + (kk & 1) * 8) = st;
}

// ---------------------------------------------------------------------------
// fp8 MFMA GEMM, kv-proj + q-proj in ONE launch (grid 2560), 128x64 tile,
// BK=128, 4 waves (wave tile 64x32), single-buffered 24KB LDS -> 6 blocks/CU
// for TLP-based latency hiding. XCD-aware swizzle (m-octet per XCD).
//   kv (bid<2048):  j=bid>>3; m0=((bid&7)*8+(j&7))*128, n0=(j>>3)*64
//   q  (bid>=2048): d2=bid-2048; j=d2>>3; m0=((d2&7)*4+(j&3))*128, n0=(j>>2)*64
// Weights pre-scaled x32 -> epilogue x1/32.
// ---------------------------------------------------------------------------
__global__ __launch_bounds__(256)
void mmfp8_kernel(const unsigned char* __restrict__ c8,
                  const unsigned char* __restrict__ wkv8,
                  const unsigned char* __restrict__ wq8,
                  unsigned short* __restrict__ kraw,
                  unsigned short* __restrict__ vraw,
                  unsigned short* __restrict__ qraw)
{
    __shared__ unsigned char As[128 * 128];   // 16KB
    __shared__ unsigned char Bs[64 * 128];    // 8KB

    const int bid = blockIdx.x;
    const unsigned char *A8, *B8;
    unsigned short *outK, *outV;
    int m0, n0;
    if (bid < 2048) {
        int o = bid & 7, j = bid >> 3;
        m0 = (o * 8 + (j & 7)) * 128;
        n0 = (j >> 3) * 64;
        A8 = c8; B8 = wkv8; outK = kraw; outV = vraw;
    } else {
        int d2 = bid - 2048;
        int o = d2 & 7, j = d2 >> 3;
        m0 = (o * 4 + (j & 3)) * 128;
        n0 = (j >> 2) * 64;
        A8 = c8 + 4194304; B8 = wq8; outK = qraw; outV = nullptr;
    }

    const int t  = threadIdx.x;
    const int w  = t >> 6;
    const int l  = t & 63;
    const int lj = l & 15;
    const int lg = l >> 4;
    const int wr = w >> 1, wc = w & 1;

    const int lrow8 = l >> 3;
    const int gsw   = (l & 7) ^ lrow8;

    v4f acc[4][2] = {};

    for (int s = 0; s < 8; ++s) {
        __syncthreads();
        #pragma unroll
        for (int u = 0; u < 4; ++u) {
            int i  = w * 4 + u;
            int so = (i * 8 + lrow8) * 1024 + s * 128 + gsw * 16;
            gll16(A8 + (size_t)m0 * 1024 + so, (char*)As + i * 1024);
        }
        #pragma unroll
        for (int u = 0; u < 2; ++u) {
            int i  = w * 2 + u;
            int so = (i * 8 + lrow8) * 1024 + s * 128 + gsw * 16;
            gll16(B8 + (size_t)n0 * 1024 + so, (char*)Bs + i * 1024);
        }
        __syncthreads();

        lx2 a2[4][2], b2[2][2];
        #pragma unroll
        for (int m = 0; m < 4; ++m) {
            int row = wr * 64 + m * 16 + lj;
            #pragma unroll
            for (int gp = 0; gp < 2; ++gp) {
                int gr = lg * 2 + gp;
                a2[m][gp] = *(const lx2*)(As + row * 128 + ((gr ^ (row & 7)) * 16));
            }
        }
        #pragma unroll
        for (int nn = 0; nn < 2; ++nn) {
            int row = wc * 32 + nn * 16 + lj;
            #pragma unroll
            for (int gp = 0; gp < 2; ++gp) {
                int gr = lg * 2 + gp;
                b2[nn][gp] = *(const lx2*)(Bs + row * 128 + ((gr ^ (row & 7)) * 16));
            }
        }
        __builtin_amdgcn_s_setprio(1);
        #pragma unroll
        for (int kk = 0; kk < 4; ++kk) {
            #pragma unroll
            for (int m = 0; m < 4; ++m)
                #pragma unroll
                for (int nn = 0; nn < 2; ++nn)
                    acc[m][nn] = __builtin_amdgcn_mfma_f32_16x16x32_fp8_fp8(
                                     a2[m][kk >> 1][kk & 1], b2[nn][kk >> 1][kk & 1],
                                     acc[m][nn], 0, 0, 0);
        }
        __builtin_amdgcn_s_setprio(0);
    }

    #pragma unroll
    for (int m = 0; m < 4; ++m) {
        #pragma unroll
        for (int rr = 0; rr < 4; ++rr) {
            int row = m0 + wr * 64 + m * 16 + 4 * lg + rr;
            #pragma unroll
            for (int nn = 0; nn < 2; ++nn) {
                int col = n0 + wc * 32 + nn * 16 + lj;
                float v = acc[m][nn][rr] * 0.03125f;   // undo weight x32
                if (n0 < 1024) outK[(size_t)row * 1024 + col] = f2bf(v);
                else           outV[(size_t)row * 1024 + (col - 1024)] = f2bf(v);
            }
        }
    }
}

// ---------------------------------------------------------------------------
// Pure bf16 MFMA GEMM, 128x128 tile, BK=64 (o-proj): xo f32 = C + hres
// ---------------------------------------------------------------------------
__global__ __launch_bounds__(256)
void mm128_kernel(const unsigned short* __restrict__ Abf,
                  const unsigned short* __restrict__ Bbf,
                  const float* __restrict__ hres,
                  float* __restrict__ xo)
{
    __shared__ unsigned short As[128 * 64];
    __shared__ unsigned short Bs[128 * 64];

    const int t  = threadIdx.x;
    const int w  = t >> 6;
    const int l  = t & 63;
    const int lj = l & 15;
    const int lg = l >> 4;
    const int m0 = blockIdx.x * 128;
    const int n0 = blockIdx.y * 128;
    const int wr = w >> 1, wc = w & 1;
    const int rsub = l >> 3;
    const int csw  = ((l & 7) ^ rsub) * 16;

    v4f acc[4][4] = {};

    for (int s = 0; s < 16; ++s) {
        const int k0b = s * 128;
        __syncthreads();
        #pragma unroll
        for (int u = 0; u < 4; ++u) {
            int ra = w * 32 + u * 8;
            gll16((const char*)Abf + (size_t)(m0 + ra + rsub) * 2048 + k0b + csw,
                  (char*)As + ra * 128);
            gll16((const char*)Bbf + (size_t)(n0 + ra + rsub) * 2048 + k0b + csw,
                  (char*)Bs + ra * 128);
        }
        __syncthreads();
        #pragma unroll
        for (int ks = 0; ks < 2; ++ks) {
            bf16x8 af[4], bfr[4];
            #pragma unroll
            for (int m = 0; m < 4; ++m) {
                int row = wr * 64 + m * 16 + lj;
                int c = ks * 4 + lg;
                af[m] = *(const bf16x8*)((const char*)As + row * 128 +
                                         ((c ^ (row & 7)) * 16));
            }
            #pragma unroll
            for (int nn = 0; nn < 4; ++nn) {
                int row = wc * 64 + nn * 16 + lj;
                int c = ks * 4 + lg;
                bfr[nn] = *(const bf16x8*)((const char*)Bs + row * 128 +
                                           ((c ^ (row & 7)) * 16));
            }
            #pragma unroll
            for (int m = 0; m < 4; ++m)
                #pragma unroll
                for (int nn = 0; nn < 4; ++nn)
                    acc[m][nn] = __builtin_amdgcn_mfma_f32_16x16x32_bf16(
                                     af[m], bfr[nn], acc[m][nn], 0, 0, 0);
        }
    }

    #pragma unroll
    for (int m = 0; m < 4; ++m) {
        #pragma unroll
        for (int rr = 0; rr < 4; ++rr) {
            int row = m0 + wr * 64 + m * 16 + 4 * lg + rr;
            #pragma unroll
            for (int nn = 0; nn < 4; ++nn) {
                int col = n0 + wc * 64 + nn * 16 + lj;
                xo[(size_t)row * 1024 + col] =
                    acc[m][nn][rr] + hres[(size_t)row * 1024 + col];
            }
        }
    }
}

// ---------------------------------------------------------------------------
// Merged DPFP features + V transpose (one launch).
// blocks [0,1536): dpfp; [1536,2048): vtrans.
// ---------------------------------------------------------------------------
__device__ __forceinline__ float gld(const unsigned short* gr, int idx) {
    return __builtin_bit_cast(float, ((unsigned int)gr[idx]) << 16);
}

template<int FBASE>
__device__ __forceinline__ void dpfp_half8(const unsigned short* __restrict__ gr,
                                           unsigned char* __restrict__ drow)
{
    #pragma unroll
    for (int c = 0; c < 12; ++c) {
        unsigned int w4[4];
        #pragma unroll
        for (int q4 = 0; q4 < 4; ++q4) {
            float p[4];
            #pragma unroll
            for (int e = 0; e < 4; ++e) {
                const int f  = FBASE + c * 16 + q4 * 4 + e;
                const int r  = (f >> 7) + 1;
                const int tt = f & 127;
                const int uu = (tt - r) & 127;
                p[e] = gld(gr, tt) * gld(gr, uu);
            }
            int v = __builtin_amdgcn_cvt_pk_fp8_f32(p[0], p[1], 0, false);
            v     = __builtin_amdgcn_cvt_pk_fp8_f32(p[2], p[3], v, true);
            w4[q4] = (unsigned int)v;
        }
        u32x4 st = {w4[0], w4[1], w4[2], w4[3]};
        *(u32x4*)(drow + c * 1024) = st;
    }
}

__global__ __launch_bounds__(256)
void feat_kernel(const unsigned short* __restrict__ qraw,
                 const unsigned short* __restrict__ kraw,
                 const unsigned short* __restrict__ vraw,
                 unsigned char* __restrict__ qf, unsigned char* __restrict__ kf,
                 unsigned short* __restrict__ vt)
{
    __shared__ __align__(16) char smem[36864];
    const int t   = threadIdx.x;
    const int blk = blockIdx.x;

    if (blk >= 1536) {
        unsigned short (*S)[72] = (unsigned short(*)[72])smem;
        int v = blk - 1536;
        int jc = v & 3, hh = (v >> 2) & 15, b = v >> 6;
        const unsigned short* src = vraw + (size_t)((jc * 256 + t) * 8 + b) * 1024 + hh * 64;
        #pragma unroll
        for (int c = 0; c < 8; ++c)
            *(u32x4*)&S[t][c * 8] = *(const u32x4*)(src + c * 8);
        __syncthreads();
        const int d = t >> 2, qq = t & 3;
        unsigned short* dst = vt + ((size_t)(b * NH + hh) * HD + d) * KLEN + jc * 256 + qq * 64;
        #pragma unroll
        for (int c8 = 0; c8 < 8; ++c8) {
            u16x8 o;
            #pragma unroll
            for (int e = 0; e < 8; ++e) o[e] = S[qq * 64 + c8 * 8 + e][d];
            *(u16x8*)(dst + c8 * 8) = o;
        }
        return;
    }

    unsigned short* G = (unsigned short*)smem;   // [128][138]
    const unsigned short* src; unsigned char* dst; int b, hh, seq0;
    if (blk < 512) {
        int bh = blk >> 2, ig = blk & 3;
        b = bh >> 4; hh = bh & 15; seq0 = ig * 128;
        src = qraw; dst = qf + (size_t)bh * 196608;
    } else {
        int blk2 = blk - 512;
        int bh = blk2 >> 3, jg = blk2 & 7;
        b = bh >> 4; hh = bh & 15; seq0 = jg * 128;
        src = kraw; dst = kf + (size_t)bh * 393216;
    }

    #pragma unroll
    for (int p = 0; p < 4; ++p) {
        int u   = p * 256 + t;
        int row = u >> 3;
        int c0  = (u & 7) * 8;
        u32x4 x = *(const u32x4*)(src + ((size_t)(seq0 + row) * 8 + b) * 1024 +
                                  hh * 64 + c0);
        char* gbase = (char*)G + row * 276 + c0 * 2;
        #pragma unroll
        for (int k = 0; k < 4; ++k) {
            unsigned int xk = x[k];
            float x0 = __builtin_bit_cast(float, xk << 16);
            float x1 = __builtin_bit_cast(float, xk & 0xffff0000u);
            float a0 = fmaxf(x0, 0.f), a1 = fmaxf(x1, 0.f);
            float b0 = fmaxf(-x0, 0.f), b1 = fmaxf(-x1, 0.f);
            unsigned int lo, hig;
            asm("v_cvt_pk_bf16_f32 %0, %1, %2" : "=v"(lo) : "v"(a0), "v"(a1));
            asm("v_cvt_pk_bf16_f32 %0, %1, %2" : "=v"(hig) : "v"(b0), "v"(b1));
            *(unsigned int*)(gbase + k * 4)       = lo;
            *(unsigned int*)(gbase + 128 + k * 4) = hig;
        }
    }
    __syncthreads();

    const int w    = t >> 6;
    const int l    = t & 63;
    const int rowc = (w >> 1) * 64 + l;
    const int hs   = w & 1;
    const unsigned short* gr = G + rowc * 138;
    const int seq = seq0 + rowc;
    unsigned char* drow = dst + (size_t)(seq >> 6) * 24576 + (seq & 63) * 16 +
                          hs * 12288;
    if (hs == 0) dpfp_half8<0>(gr, drow);
    else         dpfp_half8<192>(gr, drow);
}

// ---------------------------------------------------------------------------
// MFMA attention (proven 4-wave): fp8 QK^T (swapped), in-reg P via cvt_pk +
// permlane32_swap, bf16 PV. K staged LINEAR. KVBLK=64, 4 waves x 32 i.
// ---------------------------------------------------------------------------
__global__ __launch_bounds__(256, 2)
void attn_mfma_kernel(const unsigned char* __restrict__ qf,
                      const unsigned char* __restrict__ kf,
                      const unsigned short* __restrict__ vt,
                      unsigned short* __restrict__ avec)
{
    __shared__ unsigned char Ks[64 * 384];    // 24KB fp8: [cell24][row64][16B]
    __shared__ unsigned short Vs[64 * 64];    // 8KB bf16: rows(d) 128B, swizzled
    __shared__ float Ds[4][32];

    const int t  = threadIdx.x;
    const int w  = t >> 6;
    const int l  = t & 63;
    const int li = l & 31;
    const int hi = l >> 5;

    const int bid = blockIdx.x;
    const int it  = (bid >> 3) & 3;
    const int P   = ((bid >> 5) << 3) + (bid & 7);
    const int n   = P & 15;
    const int b   = P >> 4;

    const unsigned char* qpan = qf + (size_t)P * 196608;
    const unsigned char* kpan = kf + (size_t)P * 393216;
    const char* vpan = (const char*)(vt + (size_t)P * HD * KLEN);

    int voff[2];
    #pragma unroll
    for (int uu = 0; uu < 2; ++uu) {
        int s  = (w * 2 + uu) * 64 + l;
        int d  = s >> 3;
        int cl = s & 7;
        int cg = cl ^ (d & 7);
        voff[uu] = d * (KLEN * 2) + cg * 16;
    }

    long qfr[24];
    {
        const unsigned char* qb = qpan + (size_t)(it * 2 + (w >> 1)) * 24576 +
                                  ((w & 1) * 32 + li) * 16 + hi * 8;
        #pragma unroll
        for (int ks = 0; ks < 24; ++ks)
            qfr[ks] = *(const long*)(qb + ks * 1024);
    }

    f32x16 num[2] = {};
    float den_acc = 0.f;

    const int ig         = it * 128 + w * 32 + li;
    const int my_jt_end  = 2 * it + 8 + (w >> 1);
    const int jt_blk_end = 2 * it + 9;

    for (int jt = 0; jt <= jt_blk_end; ++jt) {
        __syncthreads();
        const unsigned char* ktile = kpan + (size_t)jt * 24576;
        #pragma unroll
        for (int u = 0; u < 6; ++u)
            gll16(ktile + (w * 6 + u) * 1024 + l * 16, Ks + (w * 6 + u) * 1024);
        const char* vtile = vpan + jt * 128;
        #pragma unroll
        for (int uu = 0; uu < 2; ++uu)
            gll16(vtile + voff[uu], (char*)Vs + (w * 2 + uu) * 1024);
        __syncthreads();

        if (jt > my_jt_end) continue;

        f32x16 sacc0 = {};
        f32x16 sacc1 = {};
        __builtin_amdgcn_s_setprio(1);
        #pragma unroll
        for (int ks = 0; ks < 24; ++ks) {
            long k0 = *(const long*)(Ks + ks * 1024 + li * 16 + hi * 8);
            long k1 = *(const long*)(Ks + ks * 1024 + (32 + li) * 16 + hi * 8);
            sacc0 = __builtin_amdgcn_mfma_f32_32x32x16_fp8_fp8(k0, qfr[ks], sacc0, 0, 0, 0);
            sacc1 = __builtin_amdgcn_mfma_f32_32x32x16_fp8_fp8(k1, qfr[ks], sacc1, 0, 0, 0);
        }
        __builtin_amdgcn_s_setprio(0);

        if (jt == my_jt_end) {
            const int joff = jt * 64 - MLEN + 4 * hi;
            #pragma unroll
            for (int reg = 0; reg < 16; ++reg) {
                int jr = (reg & 3) + 8 * (reg >> 2);
                if (joff + jr > ig)      sacc0[reg] = 0.f;
                if (joff + 32 + jr > ig) sacc1[reg] = 0.f;
            }
        }
        {
            float dpart = 0.f;
            #pragma unroll
            for (int reg = 0; reg < 16; ++reg) dpart += sacc0[reg] + sacc1[reg];
            den_acc += dpart + __shfl_xor(dpart, 32);
        }

        #pragma unroll
        for (int jf = 0; jf < 2; ++jf) {
            const f32x16 sc = jf ? sacc1 : sacc0;
            unsigned int c01, c23, c45, c67, c89, cab, ccd, cef;
            asm("v_cvt_pk_bf16_f32 %0, %1, %2" : "=v"(c01) : "v"(sc[0]),  "v"(sc[1]));
            asm("v_cvt_pk_bf16_f32 %0, %1, %2" : "=v"(c23) : "v"(sc[2]),  "v"(sc[3]));
            asm("v_cvt_pk_bf16_f32 %0, %1, %2" : "=v"(c45) : "v"(sc[4]),  "v"(sc[5]));
            asm("v_cvt_pk_bf16_f32 %0, %1, %2" : "=v"(c67) : "v"(sc[6]),  "v"(sc[7]));
            asm("v_cvt_pk_bf16_f32 %0, %1, %2" : "=v"(c89) : "v"(sc[8]),  "v"(sc[9]));
            asm("v_cvt_pk_bf16_f32 %0, %1, %2" : "=v"(cab) : "v"(sc[10]), "v"(sc[11]));
            asm("v_cvt_pk_bf16_f32 %0, %1, %2" : "=v"(ccd) : "v"(sc[12]), "v"(sc[13]));
            asm("v_cvt_pk_bf16_f32 %0, %1, %2" : "=v"(cef) : "v"(sc[14]), "v"(sc[15]));
            u32x2 r0 = __builtin_amdgcn_permlane32_swap(c01, c45, false, false);
            u32x2 r1 = __builtin_amdgcn_permlane32_swap(c23, c67, false, false);
            u32x2 r2 = __builtin_amdgcn_permlane32_swap(c89, ccd, false, false);
            u32x2 r3 = __builtin_amdgcn_permlane32_swap(cab, cef, false, false);
            u32x4 pw0 = {r0.x, r1.x, r0.y, r1.y};
            u32x4 pw1 = {r2.x, r3.x, r2.y, r3.y};
            bf16x8 pa0 = __builtin_bit_cast(bf16x8, pw0);
            bf16x8 pa1 = __builtin_bit_cast(bf16x8, pw1);
            __builtin_amdgcn_s_setprio(1);
            #pragma unroll
            for (int dd = 0; dd < 2; ++dd) {
                int d = dd * 32 + li;
                {
                    int cs = (jf * 4 + hi) ^ (d & 7);
                    bf16x8 vb = *(const bf16x8*)((const char*)Vs + d * 128 + cs * 16);
                    num[dd] = __builtin_amdgcn_mfma_f32_32x32x16_bf16(pa0, vb, num[dd], 0, 0, 0);
                }
                {
                    int cs = (jf * 4 + 2 + hi) ^ (d & 7);
                    bf16x8 vb = *(const bf16x8*)((const char*)Vs + d * 128 + cs * 16);
                    num[dd] = __builtin_amdgcn_mfma_f32_32x32x16_bf16(pa1, vb, num[dd], 0, 0, 0);
                }
            }
            __builtin_amdgcn_s_setprio(0);
        }
    }

    if (l < 32) Ds[w][l] = den_acc;
    #pragma unroll
    for (int reg = 0; reg < 16; ++reg) {
        int i_loc = (reg & 3) + 8 * (reg >> 2) + 4 * hi;
        float dv = Ds[w][i_loc];
        float minv = ATT_SCALE / (dv * ATT_SCALE + EPSV);
        int ig2 = it * 128 + w * 32 + i_loc;
        unsigned short* orow = avec + ((size_t)ig2 * BB + b) * DMODEL + n * HD;
        orow[li]      = f2bf(num[0][reg] * minv);
        orow[32 + li] = f2bf(num[1][reg] * minv);
    }
}

// ---------------------------------------------------------------------------
// Row LayerNorm over DM=1024.
// ---------------------------------------------------------------------------
__global__ __launch_bounds__(256)
void ln_kernel(const float* __restrict__ x, const float* __restrict__ gamma,
               const float* __restrict__ beta, float* __restrict__ out)
{
    const int row = blockIdx.x;
    const int t = threadIdx.x;
    const float* xr = x + (size_t)row * DMODEL;
    v4f xv = *(const v4f*)(xr + (t << 2));
    float s1 = xv[0] + xv[1] + xv[2] + xv[3];
    float s2 = xv[0]*xv[0] + xv[1]*xv[1] + xv[2]*xv[2] + xv[3]*xv[3];
    #pragma unroll
    for (int off = 32; off > 0; off >>= 1) {
        s1 += __shfl_down(s1, off);
        s2 += __shfl_down(s2, off);
    }
    __shared__ float red[2][4];
    __shared__ float mv[2];
    const int wave = t >> 6;
    if ((t & 63) == 0) { red[0][wave] = s1; red[1][wave] = s2; }
    __syncthreads();
    if (t == 0) {
        float a = red[0][0] + red[0][1] + red[0][2] + red[0][3];
        float q = red[1][0] + red[1][1] + red[1][2] + red[1][3];
        float mu  = a * (1.f / DMODEL);
        float var = q * (1.f / DMODEL) - mu * mu;
        mv[0] = mu;
        mv[1] = rsqrtf(var + EPSV);
    }
    __syncthreads();
    float mu = mv[0], rs = mv[1];
    v4f gv = *(const v4f*)(gamma + (t << 2));
    v4f bv = *(const v4f*)(beta + (t << 2));
    v4f o;
    #pragma unroll
    for (int e = 0; e < 4; ++e) o[e] = (xv[e] - mu) * rs * gv[e] + bv[e];
    *(v4f*)(out + (size_t)row * DMODEL + (t << 2)) = o;
}

extern "C" void kernel_launch(void* const* d_in, const int* in_sizes, int n_in,
                              void* d_out, int out_size, void* d_ws, size_t ws_size,
                              hipStream_t stream)
{
    const float* h     = (const float*)d_in[0];
    const float* mems  = (const float*)d_in[1];
    const float* Wq    = (const float*)d_in[2];
    const float* Wkv   = (const float*)d_in[3];
    const float* Wo    = (const float*)d_in[4];
    const float* gamma = (const float*)d_in[5];
    const float* beta  = (const float*)d_in[6];
    // d_in[7] = attn_mask: causal structure computed analytically, ignored.

    char* ws = (char*)d_ws;
    unsigned char* qf    = (unsigned char*)(ws);              // 25.17M fp8 feats
    unsigned char* kf    = (unsigned char*)(ws + 25165824);   // 50.33M fp8 feats
    unsigned char* c8    = (unsigned char*)(ws + 75497472);   // 8.39M fp8
    unsigned char* wkv8  = (unsigned char*)(ws + 83886080);   // 2.10M fp8
    unsigned char* wq8   = (unsigned char*)(ws + 85983232);   // 1.05M fp8
    unsigned short* vt   = (unsigned short*)(ws + 92274688);  // 16.78M bf16 (own region)
    unsigned short* kraw = (unsigned short*)(ws + 150994944); // 16.78M bf16
    unsigned short* vraw = (unsigned short*)(ws + 167772160); // 16.78M
    unsigned short* qraw = (unsigned short*)(ws + 184549376); // 8.39M
    unsigned short* avec = qraw;                              // overlay after feat
    float* xws = (float*)(ws);                                // overlay qf after attn

    unsigned short* wob = (unsigned short*)d_out;             // bf16 Wo in d_out

    cvt_kernel<<<6656, 256, 0, stream>>>(h, mems, Wkv, Wq, Wo, c8, wkv8, wq8, wob);
    mmfp8_kernel<<<2560, 256, 0, stream>>>(c8, wkv8, wq8, kraw, vraw, qraw);
    feat_kernel<<<2048, 256, 0, stream>>>(qraw, kraw, vraw, qf, kf, vt);
    attn_mfma_kernel<<<512, 256, 0, stream>>>(qf, kf, vt, avec);
    mm128_kernel<<<dim3(32, 8), 256, 0, stream>>>(avec, wob, h, xws);
    ln_kernel<<<4096, 256, 0, stream>>>(xws, gamma, beta, (float*)d_out);
}

// Round 19
// 144.787 us; speedup vs baseline: 1.0326x; 1.0326x over previous
//
#include <hip/hip_runtime.h>

#define QLEN 512
#define MLEN 512
#define KLEN 1024
#define BB   8
#define DMODEL 1024
#define NH   16
#define HD   64
#define NF   384
#define ATT_SCALE 0.125f
#define EPSV 1e-5f

typedef float v4f __attribute__((ext_vector_type(4)));
typedef float f32x16 __attribute__((ext_vector_type(16)));
typedef short bf16x8 __attribute__((ext_vector_type(8)));
typedef long lx2 __attribute__((ext_vector_type(2)));
typedef unsigned int u32x4 __attribute__((ext_vector_type(4)));
typedef unsigned int u32x2 __attribute__((ext_vector_type(2)));
typedef unsigned short u16x8 __attribute__((ext_vector_type(8)));

__device__ __forceinline__ unsigned short f2bf(float f) {
    unsigned int x = __builtin_bit_cast(unsigned int, f);
    x += 0x7fffu + ((x >> 16) & 1u);
    return (unsigned short)(x >> 16);
}

__device__ __forceinline__ void gll16(const void* g, void* l) {
    __builtin_amdgcn_global_load_lds(
        (const __attribute__((address_space(1))) unsigned int*)g,
        (__attribute__((address_space(3))) unsigned int*)l, 16, 0, 0);
}

// fp8 feature layout (bytes): feat[bh][rb][cell:24][row:64][16 fp8]
// fp8 GEMM row layout (1024 fp8/row), granule-permuted per 128-byte K-step:
//   k = kstep*128 + kk*32 + lg*8 + e  <->  byte = kstep*128 + (lg*2+(kk>>1))*16 + (kk&1)*8 + e

// ---------------------------------------------------------------------------
// Merged converts: blocks [0,5632) = fp8 (c rows, Wkv x32, Wq x32);
// blocks [5632,6656) = Wo -> bf16.
// ---------------------------------------------------------------------------
__global__ __launch_bounds__(256)
void cvt_kernel(const float* __restrict__ h, const float* __restrict__ mems,
                const float* __restrict__ Wkv, const float* __restrict__ Wq,
                const float* __restrict__ Wo,
                unsigned char* __restrict__ c8, unsigned char* __restrict__ wkv8,
                unsigned char* __restrict__ wq8, unsigned short* __restrict__ wob)
{
    int blk = blockIdx.x;
    if (blk >= 5632) {
        int i = ((blk - 5632) * 256 + threadIdx.x) * 4;
        v4f v = *(const v4f*)(Wo + i);
        unsigned int p0, p1;
        asm("v_cvt_pk_bf16_f32 %0, %1, %2" : "=v"(p0) : "v"(v[0]), "v"(v[1]));
        asm("v_cvt_pk_bf16_f32 %0, %1, %2" : "=v"(p1) : "v"(v[2]), "v"(v[3]));
        uint2 u; u.x = p0; u.y = p1;
        *(uint2*)(wob + i) = u;
        return;
    }
    int tid = blk * 256 + threadIdx.x;
    const float* src; unsigned char* dstrow; float scale; int row, k0;
    if (tid < 1048576) {               // c: 8192 rows
        int base = tid * 8; row = base >> 10; k0 = base & 1023;
        src = (row < 4096) ? (mems + (size_t)row * 1024)
                           : (h + (size_t)(row - 4096) * 1024);
        dstrow = c8 + (size_t)row * 1024; scale = 1.f;
    } else if (tid < 1310720) {        // Wkv: 2048 rows, x32
        int t2 = tid - 1048576; int base = t2 * 8; row = base >> 10; k0 = base & 1023;
        src = Wkv + (size_t)row * 1024; dstrow = wkv8 + (size_t)row * 1024; scale = 32.f;
    } else {                           // Wq: 1024 rows, x32
        int t2 = tid - 1310720; int base = t2 * 8; row = base >> 10; k0 = base & 1023;
        src = Wq + (size_t)row * 1024; dstrow = wq8 + (size_t)row * 1024; scale = 32.f;
    }
    v4f a = *(const v4f*)(src + k0);
    v4f b = *(const v4f*)(src + k0 + 4);
    int v0 = __builtin_amdgcn_cvt_pk_fp8_f32(a[0]*scale, a[1]*scale, 0, false);
    v0     = __builtin_amdgcn_cvt_pk_fp8_f32(a[2]*scale, a[3]*scale, v0, true);
    int v1 = __builtin_amdgcn_cvt_pk_fp8_f32(b[0]*scale, b[1]*scale, 0, false);
    v1     = __builtin_amdgcn_cvt_pk_fp8_f32(b[2]*scale, b[3]*scale, v1, true);
    int kk = (k0 & 127) >> 5;
    int lg = (k0 & 31) >> 3;
    uint2 st; st.x = (unsigned int)v0; st.y = (unsigned int)v1;
    *(uint2*)(dstrow + (k0 & ~127) + (lg * 2 + (kk >> 1)) * 16 + (kk & 1) * 8) = st;
}

// ---------------------------------------------------------------------------
// fp8 MFMA GEMM, kv-proj + q-proj in ONE launch (grid 2560), 128x64 tile,
// BK=128, 4 waves, single-buffered 24KB LDS. XCD-aware swizzle.
// ---------------------------------------------------------------------------
__global__ __launch_bounds__(256)
void mmfp8_kernel(const unsigned char* __restrict__ c8,
                  const unsigned char* __restrict__ wkv8,
                  const unsigned char* __restrict__ wq8,
                  unsigned short* __restrict__ kraw,
                  unsigned short* __restrict__ vraw,
                  unsigned short* __restrict__ qraw)
{
    __shared__ unsigned char As[128 * 128];   // 16KB
    __shared__ unsigned char Bs[64 * 128];    // 8KB

    const int bid = blockIdx.x;
    const unsigned char *A8, *B8;
    unsigned short *outK, *outV;
    int m0, n0;
    if (bid < 2048) {
        int o = bid & 7, j = bid >> 3;
        m0 = (o * 8 + (j & 7)) * 128;
        n0 = (j >> 3) * 64;
        A8 = c8; B8 = wkv8; outK = kraw; outV = vraw;
    } else {
        int d2 = bid - 2048;
        int o = d2 & 7, j = d2 >> 3;
        m0 = (o * 4 + (j & 3)) * 128;
        n0 = (j >> 2) * 64;
        A8 = c8 + 4194304; B8 = wq8; outK = qraw; outV = nullptr;
    }

    const int t  = threadIdx.x;
    const int w  = t >> 6;
    const int l  = t & 63;
    const int lj = l & 15;
    const int lg = l >> 4;
    const int wr = w >> 1, wc = w & 1;

    const int lrow8 = l >> 3;
    const int gsw   = (l & 7) ^ lrow8;

    v4f acc[4][2] = {};

    for (int s = 0; s < 8; ++s) {
        __syncthreads();
        #pragma unroll
        for (int u = 0; u < 4; ++u) {
            int i  = w * 4 + u;
            int so = (i * 8 + lrow8) * 1024 + s * 128 + gsw * 16;
            gll16(A8 + (size_t)m0 * 1024 + so, (char*)As + i * 1024);
        }
        #pragma unroll
        for (int u = 0; u < 2; ++u) {
            int i  = w * 2 + u;
            int so = (i * 8 + lrow8) * 1024 + s * 128 + gsw * 16;
            gll16(B8 + (size_t)n0 * 1024 + so, (char*)Bs + i * 1024);
        }
        __syncthreads();

        lx2 a2[4][2], b2[2][2];
        #pragma unroll
        for (int m = 0; m < 4; ++m) {
            int row = wr * 64 + m * 16 + lj;
            #pragma unroll
            for (int gp = 0; gp < 2; ++gp) {
                int gr = lg * 2 + gp;
                a2[m][gp] = *(const lx2*)(As + row * 128 + ((gr ^ (row & 7)) * 16));
            }
        }
        #pragma unroll
        for (int nn = 0; nn < 2; ++nn) {
            int row = wc * 32 + nn * 16 + lj;
            #pragma unroll
            for (int gp = 0; gp < 2; ++gp) {
                int gr = lg * 2 + gp;
                b2[nn][gp] = *(const lx2*)(Bs + row * 128 + ((gr ^ (row & 7)) * 16));
            }
        }
        __builtin_amdgcn_s_setprio(1);
        #pragma unroll
        for (int kk = 0; kk < 4; ++kk) {
            #pragma unroll
            for (int m = 0; m < 4; ++m)
                #pragma unroll
                for (int nn = 0; nn < 2; ++nn)
                    acc[m][nn] = __builtin_amdgcn_mfma_f32_16x16x32_fp8_fp8(
                                     a2[m][kk >> 1][kk & 1], b2[nn][kk >> 1][kk & 1],
                                     acc[m][nn], 0, 0, 0);
        }
        __builtin_amdgcn_s_setprio(0);
    }

    #pragma unroll
    for (int m = 0; m < 4; ++m) {
        #pragma unroll
        for (int rr = 0; rr < 4; ++rr) {
            int row = m0 + wr * 64 + m * 16 + 4 * lg + rr;
            #pragma unroll
            for (int nn = 0; nn < 2; ++nn) {
                int col = n0 + wc * 32 + nn * 16 + lj;
                float v = acc[m][nn][rr] * 0.03125f;   // undo weight x32
                if (n0 < 1024) outK[(size_t)row * 1024 + col] = f2bf(v);
                else           outV[(size_t)row * 1024 + (col - 1024)] = f2bf(v);
            }
        }
    }
}

// ---------------------------------------------------------------------------
// Pure bf16 MFMA GEMM, 128x128 tile, BK=64 (o-proj): xo f32 = C + hres
// ---------------------------------------------------------------------------
__global__ __launch_bounds__(256)
void mm128_kernel(const unsigned short* __restrict__ Abf,
                  const unsigned short* __restrict__ Bbf,
                  const float* __restrict__ hres,
                  float* __restrict__ xo)
{
    __shared__ unsigned short As[128 * 64];
    __shared__ unsigned short Bs[128 * 64];

    const int t  = threadIdx.x;
    const int w  = t >> 6;
    const int l  = t & 63;
    const int lj = l & 15;
    const int lg = l >> 4;
    const int m0 = blockIdx.x * 128;
    const int n0 = blockIdx.y * 128;
    const int wr = w >> 1, wc = w & 1;
    const int rsub = l >> 3;
    const int csw  = ((l & 7) ^ rsub) * 16;

    v4f acc[4][4] = {};

    for (int s = 0; s < 16; ++s) {
        const int k0b = s * 128;
        __syncthreads();
        #pragma unroll
        for (int u = 0; u < 4; ++u) {
            int ra = w * 32 + u * 8;
            gll16((const char*)Abf + (size_t)(m0 + ra + rsub) * 2048 + k0b + csw,
                  (char*)As + ra * 128);
            gll16((const char*)Bbf + (size_t)(n0 + ra + rsub) * 2048 + k0b + csw,
                  (char*)Bs + ra * 128);
        }
        __syncthreads();
        #pragma unroll
        for (int ks = 0; ks < 2; ++ks) {
            bf16x8 af[4], bfr[4];
            #pragma unroll
            for (int m = 0; m < 4; ++m) {
                int row = wr * 64 + m * 16 + lj;
                int c = ks * 4 + lg;
                af[m] = *(const bf16x8*)((const char*)As + row * 128 +
                                         ((c ^ (row & 7)) * 16));
            }
            #pragma unroll
            for (int nn = 0; nn < 4; ++nn) {
                int row = wc * 64 + nn * 16 + lj;
                int c = ks * 4 + lg;
                bfr[nn] = *(const bf16x8*)((const char*)Bs + row * 128 +
                                           ((c ^ (row & 7)) * 16));
            }
            #pragma unroll
            for (int m = 0; m < 4; ++m)
                #pragma unroll
                for (int nn = 0; nn < 4; ++nn)
                    acc[m][nn] = __builtin_amdgcn_mfma_f32_16x16x32_bf16(
                                     af[m], bfr[nn], acc[m][nn], 0, 0, 0);
        }
    }

    #pragma unroll
    for (int m = 0; m < 4; ++m) {
        #pragma unroll
        for (int rr = 0; rr < 4; ++rr) {
            int row = m0 + wr * 64 + m * 16 + 4 * lg + rr;
            #pragma unroll
            for (int nn = 0; nn < 4; ++nn) {
                int col = n0 + wc * 64 + nn * 16 + lj;
                xo[(size_t)row * 1024 + col] =
                    acc[m][nn][rr] + hres[(size_t)row * 1024 + col];
            }
        }
    }
}

// ---------------------------------------------------------------------------
// Merged DPFP features + V transpose (one launch).
// blocks [0,1536): dpfp; [1536,2048): vtrans.
// ---------------------------------------------------------------------------
__device__ __forceinline__ float gld(const unsigned short* gr, int idx) {
    return __builtin_bit_cast(float, ((unsigned int)gr[idx]) << 16);
}

template<int FBASE>
__device__ __forceinline__ void dpfp_half8(const unsigned short* __restrict__ gr,
                                           unsigned char* __restrict__ drow)
{
    #pragma unroll
    for (int c = 0; c < 12; ++c) {
        unsigned int w4[4];
        #pragma unroll
        for (int q4 = 0; q4 < 4; ++q4) {
            float p[4];
            #pragma unroll
            for (int e = 0; e < 4; ++e) {
                const int f  = FBASE + c * 16 + q4 * 4 + e;
                const int r  = (f >> 7) + 1;
                const int tt = f & 127;
                const int uu = (tt - r) & 127;
                p[e] = gld(gr, tt) * gld(gr, uu);
            }
            int v = __builtin_amdgcn_cvt_pk_fp8_f32(p[0], p[1], 0, false);
            v     = __builtin_amdgcn_cvt_pk_fp8_f32(p[2], p[3], v, true);
            w4[q4] = (unsigned int)v;
        }
        u32x4 st = {w4[0], w4[1], w4[2], w4[3]};
        *(u32x4*)(drow + c * 1024) = st;
    }
}

__global__ __launch_bounds__(256)
void feat_kernel(const unsigned short* __restrict__ qraw,
                 const unsigned short* __restrict__ kraw,
                 const unsigned short* __restrict__ vraw,
                 unsigned char* __restrict__ qf, unsigned char* __restrict__ kf,
                 unsigned short* __restrict__ vt)
{
    __shared__ __align__(16) char smem[36864];
    const int t   = threadIdx.x;
    const int blk = blockIdx.x;

    if (blk >= 1536) {
        unsigned short (*S)[72] = (unsigned short(*)[72])smem;
        int v = blk - 1536;
        int jc = v & 3, hh = (v >> 2) & 15, b = v >> 6;
        const unsigned short* src = vraw + (size_t)((jc * 256 + t) * 8 + b) * 1024 + hh * 64;
        #pragma unroll
        for (int c = 0; c < 8; ++c)
            *(u32x4*)&S[t][c * 8] = *(const u32x4*)(src + c * 8);
        __syncthreads();
        const int d = t >> 2, qq = t & 3;
        unsigned short* dst = vt + ((size_t)(b * NH + hh) * HD + d) * KLEN + jc * 256 + qq * 64;
        #pragma unroll
        for (int c8 = 0; c8 < 8; ++c8) {
            u16x8 o;
            #pragma unroll
            for (int e = 0; e < 8; ++e) o[e] = S[qq * 64 + c8 * 8 + e][d];
            *(u16x8*)(dst + c8 * 8) = o;
        }
        return;
    }

    unsigned short* G = (unsigned short*)smem;   // [128][138]
    const unsigned short* src; unsigned char* dst; int b, hh, seq0;
    if (blk < 512) {
        int bh = blk >> 2, ig = blk & 3;
        b = bh >> 4; hh = bh & 15; seq0 = ig * 128;
        src = qraw; dst = qf + (size_t)bh * 196608;
    } else {
        int blk2 = blk - 512;
        int bh = blk2 >> 3, jg = blk2 & 7;
        b = bh >> 4; hh = bh & 15; seq0 = jg * 128;
        src = kraw; dst = kf + (size_t)bh * 393216;
    }

    #pragma unroll
    for (int p = 0; p < 4; ++p) {
        int u   = p * 256 + t;
        int row = u >> 3;
        int c0  = (u & 7) * 8;
        u32x4 x = *(const u32x4*)(src + ((size_t)(seq0 + row) * 8 + b) * 1024 +
                                  hh * 64 + c0);
        char* gbase = (char*)G + row * 276 + c0 * 2;
        #pragma unroll
        for (int k = 0; k < 4; ++k) {
            unsigned int xk = x[k];
            float x0 = __builtin_bit_cast(float, xk << 16);
            float x1 = __builtin_bit_cast(float, xk & 0xffff0000u);
            float a0 = fmaxf(x0, 0.f), a1 = fmaxf(x1, 0.f);
            float b0 = fmaxf(-x0, 0.f), b1 = fmaxf(-x1, 0.f);
            unsigned int lo, hig;
            asm("v_cvt_pk_bf16_f32 %0, %1, %2" : "=v"(lo) : "v"(a0), "v"(a1));
            asm("v_cvt_pk_bf16_f32 %0, %1, %2" : "=v"(hig) : "v"(b0), "v"(b1));
            *(unsigned int*)(gbase + k * 4)       = lo;
            *(unsigned int*)(gbase + 128 + k * 4) = hig;
        }
    }
    __syncthreads();

    const int w    = t >> 6;
    const int l    = t & 63;
    const int rowc = (w >> 1) * 64 + l;
    const int hs   = w & 1;
    const unsigned short* gr = G + rowc * 138;
    const int seq = seq0 + rowc;
    unsigned char* drow = dst + (size_t)(seq >> 6) * 24576 + (seq & 63) * 16 +
                          hs * 12288;
    if (hs == 0) dpfp_half8<0>(gr, drow);
    else         dpfp_half8<192>(gr, drow);
}

// ---------------------------------------------------------------------------
// MFMA attention: fp8 QK^T (swapped), in-reg P via cvt_pk + permlane32_swap,
// bf16 PV. KVBLK=64, 4 waves x 32 i. Complementary it-pairing: block k and
// k+256 (same CU under in-order dispatch) get it and 3-it, so per-CU work
// (2it+10)+(2(3-it)+10) = 26 tile-steps is constant (was 20..32).
// ---------------------------------------------------------------------------
__global__ __launch_bounds__(256, 2)
void attn_mfma_kernel(const unsigned char* __restrict__ qf,
                      const unsigned char* __restrict__ kf,
                      const unsigned short* __restrict__ vt,
                      unsigned short* __restrict__ avec)
{
    __shared__ unsigned char Ks[64 * 384];    // 24KB fp8: [cell24][row64][16B]
    __shared__ unsigned short Vs[64 * 64];    // 8KB bf16: rows(d) 128B, swizzled
    __shared__ float Ds[4][32];

    const int t  = threadIdx.x;
    const int w  = t >> 6;
    const int l  = t & 63;
    const int li = l & 31;
    const int hi = l >> 5;

    const int bid = blockIdx.x;
    const int it  = (((bid >> 3) & 3)) ^ ((((bid >> 8) & 1)) * 3);
    const int P   = ((bid >> 5) << 3) + (bid & 7);
    const int n   = P & 15;
    const int b   = P >> 4;

    const unsigned char* qpan = qf + (size_t)P * 196608;
    const unsigned char* kpan = kf + (size_t)P * 393216;
    const char* vpan = (const char*)(vt + (size_t)P * HD * KLEN);

    int voff[2];
    #pragma unroll
    for (int uu = 0; uu < 2; ++uu) {
        int s  = (w * 2 + uu) * 64 + l;
        int d  = s >> 3;
        int cl = s & 7;
        int cg = cl ^ (d & 7);
        voff[uu] = d * (KLEN * 2) + cg * 16;
    }

    long qfr[24];
    {
        const unsigned char* qb = qpan + (size_t)(it * 2 + (w >> 1)) * 24576 +
                                  ((w & 1) * 32 + li) * 16 + hi * 8;
        #pragma unroll
        for (int ks = 0; ks < 24; ++ks)
            qfr[ks] = *(const long*)(qb + ks * 1024);
    }

    f32x16 num[2] = {};
    float den_acc = 0.f;

    const int ig         = it * 128 + w * 32 + li;
    const int my_jt_end  = 2 * it + 8 + (w >> 1);
    const int jt_blk_end = 2 * it + 9;

    for (int jt = 0; jt <= jt_blk_end; ++jt) {
        __syncthreads();
        const unsigned char* ktile = kpan + (size_t)jt * 24576;
        #pragma unroll
        for (int u = 0; u < 6; ++u)
            gll16(ktile + (w * 6 + u) * 1024 + l * 16, Ks + (w * 6 + u) * 1024);
        const char* vtile = vpan + jt * 128;
        #pragma unroll
        for (int uu = 0; uu < 2; ++uu)
            gll16(vtile + voff[uu], (char*)Vs + (w * 2 + uu) * 1024);
        __syncthreads();

        if (jt > my_jt_end) continue;

        f32x16 sacc0 = {};
        f32x16 sacc1 = {};
        __builtin_amdgcn_s_setprio(1);
        #pragma unroll
        for (int ks = 0; ks < 24; ++ks) {
            long k0 = *(const long*)(Ks + ks * 1024 + li * 16 + hi * 8);
            long k1 = *(const long*)(Ks + ks * 1024 + (32 + li) * 16 + hi * 8);
            sacc0 = __builtin_amdgcn_mfma_f32_32x32x16_fp8_fp8(k0, qfr[ks], sacc0, 0, 0, 0);
            sacc1 = __builtin_amdgcn_mfma_f32_32x32x16_fp8_fp8(k1, qfr[ks], sacc1, 0, 0, 0);
        }
        __builtin_amdgcn_s_setprio(0);

        if (jt == my_jt_end) {
            const int joff = jt * 64 - MLEN + 4 * hi;
            #pragma unroll
            for (int reg = 0; reg < 16; ++reg) {
                int jr = (reg & 3) + 8 * (reg >> 2);
                if (joff + jr > ig)      sacc0[reg] = 0.f;
                if (joff + 32 + jr > ig) sacc1[reg] = 0.f;
            }
        }
        {
            float dpart = 0.f;
            #pragma unroll
            for (int reg = 0; reg < 16; ++reg) dpart += sacc0[reg] + sacc1[reg];
            den_acc += dpart + __shfl_xor(dpart, 32);
        }

        #pragma unroll
        for (int jf = 0; jf < 2; ++jf) {
            const f32x16 sc = jf ? sacc1 : sacc0;
            unsigned int c01, c23, c45, c67, c89, cab, ccd, cef;
            asm("v_cvt_pk_bf16_f32 %0, %1, %2" : "=v"(c01) : "v"(sc[0]),  "v"(sc[1]));
            asm("v_cvt_pk_bf16_f32 %0, %1, %2" : "=v"(c23) : "v"(sc[2]),  "v"(sc[3]));
            asm("v_cvt_pk_bf16_f32 %0, %1, %2" : "=v"(c45) : "v"(sc[4]),  "v"(sc[5]));
            asm("v_cvt_pk_bf16_f32 %0, %1, %2" : "=v"(c67) : "v"(sc[6]),  "v"(sc[7]));
            asm("v_cvt_pk_bf16_f32 %0, %1, %2" : "=v"(c89) : "v"(sc[8]),  "v"(sc[9]));
            asm("v_cvt_pk_bf16_f32 %0, %1, %2" : "=v"(cab) : "v"(sc[10]), "v"(sc[11]));
            asm("v_cvt_pk_bf16_f32 %0, %1, %2" : "=v"(ccd) : "v"(sc[12]), "v"(sc[13]));
            asm("v_cvt_pk_bf16_f32 %0, %1, %2" : "=v"(cef) : "v"(sc[14]), "v"(sc[15]));
            u32x2 r0 = __builtin_amdgcn_permlane32_swap(c01, c45, false, false);
            u32x2 r1 = __builtin_amdgcn_permlane32_swap(c23, c67, false, false);
            u32x2 r2 = __builtin_amdgcn_permlane32_swap(c89, ccd, false, false);
            u32x2 r3 = __builtin_amdgcn_permlane32_swap(cab, cef, false, false);
            u32x4 pw0 = {r0.x, r1.x, r0.y, r1.y};
            u32x4 pw1 = {r2.x, r3.x, r2.y, r3.y};
            bf16x8 pa0 = __builtin_bit_cast(bf16x8, pw0);
            bf16x8 pa1 = __builtin_bit_cast(bf16x8, pw1);
            __builtin_amdgcn_s_setprio(1);
            #pragma unroll
            for (int dd = 0; dd < 2; ++dd) {
                int d = dd * 32 + li;
                {
                    int cs = (jf * 4 + hi) ^ (d & 7);
                    bf16x8 vb = *(const bf16x8*)((const char*)Vs + d * 128 + cs * 16);
                    num[dd] = __builtin_amdgcn_mfma_f32_32x32x16_bf16(pa0, vb, num[dd], 0, 0, 0);
                }
                {
                    int cs = (jf * 4 + 2 + hi) ^ (d & 7);
                    bf16x8 vb = *(const bf16x8*)((const char*)Vs + d * 128 + cs * 16);
                    num[dd] = __builtin_amdgcn_mfma_f32_32x32x16_bf16(pa1, vb, num[dd], 0, 0, 0);
                }
            }
            __builtin_amdgcn_s_setprio(0);
        }
    }

    if (l < 32) Ds[w][l] = den_acc;
    #pragma unroll
    for (int reg = 0; reg < 16; ++reg) {
        int i_loc = (reg & 3) + 8 * (reg >> 2) + 4 * hi;
        float dv = Ds[w][i_loc];
        float minv = ATT_SCALE / (dv * ATT_SCALE + EPSV);
        int ig2 = it * 128 + w * 32 + i_loc;
        unsigned short* orow = avec + ((size_t)ig2 * BB + b) * DMODEL + n * HD;
        orow[li]      = f2bf(num[0][reg] * minv);
        orow[32 + li] = f2bf(num[1][reg] * minv);
    }
}

// ---------------------------------------------------------------------------
// Row LayerNorm over DM=1024.
// ---------------------------------------------------------------------------
__global__ __launch_bounds__(256)
void ln_kernel(const float* __restrict__ x, const float* __restrict__ gamma,
               const float* __restrict__ beta, float* __restrict__ out)
{
    const int row = blockIdx.x;
    const int t = threadIdx.x;
    const float* xr = x + (size_t)row * DMODEL;
    v4f xv = *(const v4f*)(xr + (t << 2));
    float s1 = xv[0] + xv[1] + xv[2] + xv[3];
    float s2 = xv[0]*xv[0] + xv[1]*xv[1] + xv[2]*xv[2] + xv[3]*xv[3];
    #pragma unroll
    for (int off = 32; off > 0; off >>= 1) {
        s1 += __shfl_down(s1, off);
        s2 += __shfl_down(s2, off);
    }
    __shared__ float red[2][4];
    __shared__ float mv[2];
    const int wave = t >> 6;
    if ((t & 63) == 0) { red[0][wave] = s1; red[1][wave] = s2; }
    __syncthreads();
    if (t == 0) {
        float a = red[0][0] + red[0][1] + red[0][2] + red[0][3];
        float q = red[1][0] + red[1][1] + red[1][2] + red[1][3];
        float mu  = a * (1.f / DMODEL);
        float var = q * (1.f / DMODEL) - mu * mu;
        mv[0] = mu;
        mv[1] = rsqrtf(var + EPSV);
    }
    __syncthreads();
    float mu = mv[0], rs = mv[1];
    v4f gv = *(const v4f*)(gamma + (t << 2));
    v4f bv = *(const v4f*)(beta + (t << 2));
    v4f o;
    #pragma unroll
    for (int e = 0; e < 4; ++e) o[e] = (xv[e] - mu) * rs * gv[e] + bv[e];
    *(v4f*)(out + (size_t)row * DMODEL + (t << 2)) = o;
}

extern "C" void kernel_launch(void* const* d_in, const int* in_sizes, int n_in,
                              void* d_out, int out_size, void* d_ws, size_t ws_size,
                              hipStream_t stream)
{
    const float* h     = (const float*)d_in[0];
    const float* mems  = (const float*)d_in[1];
    const float* Wq    = (const float*)d_in[2];
    const float* Wkv   = (const float*)d_in[3];
    const float* Wo    = (const float*)d_in[4];
    const float* gamma = (const float*)d_in[5];
    const float* beta  = (const float*)d_in[6];
    // d_in[7] = attn_mask: causal structure computed analytically, ignored.

    char* ws = (char*)d_ws;
    unsigned char* qf    = (unsigned char*)(ws);              // 25.17M fp8 feats
    unsigned char* kf    = (unsigned char*)(ws + 25165824);   // 50.33M fp8 feats
    unsigned char* c8    = (unsigned char*)(ws + 75497472);   // 8.39M fp8
    unsigned char* wkv8  = (unsigned char*)(ws + 83886080);   // 2.10M fp8
    unsigned char* wq8   = (unsigned char*)(ws + 85983232);   // 1.05M fp8
    unsigned short* vt   = (unsigned short*)(ws + 92274688);  // 16.78M bf16 (own region)
    unsigned short* kraw = (unsigned short*)(ws + 150994944); // 16.78M bf16
    unsigned short* vraw = (unsigned short*)(ws + 167772160); // 16.78M
    unsigned short* qraw = (unsigned short*)(ws + 184549376); // 8.39M
    unsigned short* avec = qraw;                              // overlay after feat
    float* xws = (float*)(ws);                                // overlay qf after attn

    unsigned short* wob = (unsigned short*)d_out;             // bf16 Wo in d_out

    cvt_kernel<<<6656, 256, 0, stream>>>(h, mems, Wkv, Wq, Wo, c8, wkv8, wq8, wob);
    mmfp8_kernel<<<2560, 256, 0, stream>>>(c8, wkv8, wq8, kraw, vraw, qraw);
    feat_kernel<<<2048, 256, 0, stream>>>(qraw, kraw, vraw, qf, kf, vt);
    attn_mfma_kernel<<<512, 256, 0, stream>>>(qf, kf, vt, avec);
    mm128_kernel<<<dim3(32, 8), 256, 0, stream>>>(avec, wob, h, xws);
    ln_kernel<<<4096, 256, 0, stream>>>(xws, gamma, beta, (float*)d_out);
}

// Round 20
// 141.115 us; speedup vs baseline: 1.0595x; 1.0260x over previous
//
#include <hip/hip_runtime.h>

#define QLEN 512
#define MLEN 512
#define KLEN 1024
#define BB   8
#define DMODEL 1024
#define NH   16
#define HD   64
#define NF   384
#define ATT_SCALE 0.125f
#define EPSV 1e-5f

typedef float v4f __attribute__((ext_vector_type(4)));
typedef float f32x16 __attribute__((ext_vector_type(16)));
typedef short bf16x8 __attribute__((ext_vector_type(8)));
typedef long lx2 __attribute__((ext_vector_type(2)));
typedef unsigned int u32x4 __attribute__((ext_vector_type(4)));
typedef unsigned int u32x2 __attribute__((ext_vector_type(2)));
typedef unsigned short u16x8 __attribute__((ext_vector_type(8)));

__device__ __forceinline__ unsigned short f2bf(float f) {
    unsigned int x = __builtin_bit_cast(unsigned int, f);
    x += 0x7fffu + ((x >> 16) & 1u);
    return (unsigned short)(x >> 16);
}

__device__ __forceinline__ void gll16(const void* g, void* l) {
    __builtin_amdgcn_global_load_lds(
        (const __attribute__((address_space(1))) unsigned int*)g,
        (__attribute__((address_space(3))) unsigned int*)l, 16, 0, 0);
}

// fp8 feature layout (bytes): feat[bh][rb][cell:24][row:64][16 fp8]
// fp8 GEMM row layout (1024 fp8/row), granule-permuted per 128-byte K-step:
//   k = kstep*128 + kk*32 + lg*8 + e  <->  byte = kstep*128 + (lg*2+(kk>>1))*16 + (kk&1)*8 + e

// ---------------------------------------------------------------------------
// Merged converts: blocks [0,5632) = fp8 (c rows, Wkv x32, Wq x32);
// blocks [5632,6656) = Wo -> bf16.
// ---------------------------------------------------------------------------
__global__ __launch_bounds__(256)
void cvt_kernel(const float* __restrict__ h, const float* __restrict__ mems,
                const float* __restrict__ Wkv, const float* __restrict__ Wq,
                const float* __restrict__ Wo,
                unsigned char* __restrict__ c8, unsigned char* __restrict__ wkv8,
                unsigned char* __restrict__ wq8, unsigned short* __restrict__ wob)
{
    int blk = blockIdx.x;
    if (blk >= 5632) {
        int i = ((blk - 5632) * 256 + threadIdx.x) * 4;
        v4f v = *(const v4f*)(Wo + i);
        unsigned int p0, p1;
        asm("v_cvt_pk_bf16_f32 %0, %1, %2" : "=v"(p0) : "v"(v[0]), "v"(v[1]));
        asm("v_cvt_pk_bf16_f32 %0, %1, %2" : "=v"(p1) : "v"(v[2]), "v"(v[3]));
        uint2 u; u.x = p0; u.y = p1;
        *(uint2*)(wob + i) = u;
        return;
    }
    int tid = blk * 256 + threadIdx.x;
    const float* src; unsigned char* dstrow; float scale; int row, k0;
    if (tid < 1048576) {               // c: 8192 rows
        int base = tid * 8; row = base >> 10; k0 = base & 1023;
        src = (row < 4096) ? (mems + (size_t)row * 1024)
                           : (h + (size_t)(row - 4096) * 1024);
        dstrow = c8 + (size_t)row * 1024; scale = 1.f;
    } else if (tid < 1310720) {        // Wkv: 2048 rows, x32
        int t2 = tid - 1048576; int base = t2 * 8; row = base >> 10; k0 = base & 1023;
        src = Wkv + (size_t)row * 1024; dstrow = wkv8 + (size_t)row * 1024; scale = 32.f;
    } else {                           // Wq: 1024 rows, x32
        int t2 = tid - 1310720; int base = t2 * 8; row = base >> 10; k0 = base & 1023;
        src = Wq + (size_t)row * 1024; dstrow = wq8 + (size_t)row * 1024; scale = 32.f;
    }
    v4f a = *(const v4f*)(src + k0);
    v4f b = *(const v4f*)(src + k0 + 4);
    int v0 = __builtin_amdgcn_cvt_pk_fp8_f32(a[0]*scale, a[1]*scale, 0, false);
    v0     = __builtin_amdgcn_cvt_pk_fp8_f32(a[2]*scale, a[3]*scale, v0, true);
    int v1 = __builtin_amdgcn_cvt_pk_fp8_f32(b[0]*scale, b[1]*scale, 0, false);
    v1     = __builtin_amdgcn_cvt_pk_fp8_f32(b[2]*scale, b[3]*scale, v1, true);
    int kk = (k0 & 127) >> 5;
    int lg = (k0 & 31) >> 3;
    uint2 st; st.x = (unsigned int)v0; st.y = (unsigned int)v1;
    *(uint2*)(dstrow + (k0 & ~127) + (lg * 2 + (kk >> 1)) * 16 + (kk & 1) * 8) = st;
}

// ---------------------------------------------------------------------------
// fp8 MFMA GEMM, kv-proj + q-proj in ONE launch (grid 2560), 128x64 tile,
// BK=128, 4 waves, single-buffered 24KB LDS. XCD-aware swizzle.
// ---------------------------------------------------------------------------
__global__ __launch_bounds__(256)
void mmfp8_kernel(const unsigned char* __restrict__ c8,
                  const unsigned char* __restrict__ wkv8,
                  const unsigned char* __restrict__ wq8,
                  unsigned short* __restrict__ kraw,
                  unsigned short* __restrict__ vraw,
                  unsigned short* __restrict__ qraw)
{
    __shared__ unsigned char As[128 * 128];   // 16KB
    __shared__ unsigned char Bs[64 * 128];    // 8KB

    const int bid = blockIdx.x;
    const unsigned char *A8, *B8;
    unsigned short *outK, *outV;
    int m0, n0;
    if (bid < 2048) {
        int o = bid & 7, j = bid >> 3;
        m0 = (o * 8 + (j & 7)) * 128;
        n0 = (j >> 3) * 64;
        A8 = c8; B8 = wkv8; outK = kraw; outV = vraw;
    } else {
        int d2 = bid - 2048;
        int o = d2 & 7, j = d2 >> 3;
        m0 = (o * 4 + (j & 3)) * 128;
        n0 = (j >> 2) * 64;
        A8 = c8 + 4194304; B8 = wq8; outK = qraw; outV = nullptr;
    }

    const int t  = threadIdx.x;
    const int w  = t >> 6;
    const int l  = t & 63;
    const int lj = l & 15;
    const int lg = l >> 4;
    const int wr = w >> 1, wc = w & 1;

    const int lrow8 = l >> 3;
    const int gsw   = (l & 7) ^ lrow8;

    v4f acc[4][2] = {};

    for (int s = 0; s < 8; ++s) {
        __syncthreads();
        #pragma unroll
        for (int u = 0; u < 4; ++u) {
            int i  = w * 4 + u;
            int so = (i * 8 + lrow8) * 1024 + s * 128 + gsw * 16;
            gll16(A8 + (size_t)m0 * 1024 + so, (char*)As + i * 1024);
        }
        #pragma unroll
        for (int u = 0; u < 2; ++u) {
            int i  = w * 2 + u;
            int so = (i * 8 + lrow8) * 1024 + s * 128 + gsw * 16;
            gll16(B8 + (size_t)n0 * 1024 + so, (char*)Bs + i * 1024);
        }
        __syncthreads();

        lx2 a2[4][2], b2[2][2];
        #pragma unroll
        for (int m = 0; m < 4; ++m) {
            int row = wr * 64 + m * 16 + lj;
            #pragma unroll
            for (int gp = 0; gp < 2; ++gp) {
                int gr = lg * 2 + gp;
                a2[m][gp] = *(const lx2*)(As + row * 128 + ((gr ^ (row & 7)) * 16));
            }
        }
        #pragma unroll
        for (int nn = 0; nn < 2; ++nn) {
            int row = wc * 32 + nn * 16 + lj;
            #pragma unroll
            for (int gp = 0; gp < 2; ++gp) {
                int gr = lg * 2 + gp;
                b2[nn][gp] = *(const lx2*)(Bs + row * 128 + ((gr ^ (row & 7)) * 16));
            }
        }
        __builtin_amdgcn_s_setprio(1);
        #pragma unroll
        for (int kk = 0; kk < 4; ++kk) {
            #pragma unroll
            for (int m = 0; m < 4; ++m)
                #pragma unroll
                for (int nn = 0; nn < 2; ++nn)
                    acc[m][nn] = __builtin_amdgcn_mfma_f32_16x16x32_fp8_fp8(
                                     a2[m][kk >> 1][kk & 1], b2[nn][kk >> 1][kk & 1],
                                     acc[m][nn], 0, 0, 0);
        }
        __builtin_amdgcn_s_setprio(0);
    }

    #pragma unroll
    for (int m = 0; m < 4; ++m) {
        #pragma unroll
        for (int rr = 0; rr < 4; ++rr) {
            int row = m0 + wr * 64 + m * 16 + 4 * lg + rr;
            #pragma unroll
            for (int nn = 0; nn < 2; ++nn) {
                int col = n0 + wc * 32 + nn * 16 + lj;
                float v = acc[m][nn][rr] * 0.03125f;   // undo weight x32
                if (n0 < 1024) outK[(size_t)row * 1024 + col] = f2bf(v);
                else           outV[(size_t)row * 1024 + (col - 1024)] = f2bf(v);
            }
        }
    }
}

// ---------------------------------------------------------------------------
// bf16 MFMA GEMM (o-proj): 128x64 tile, BK=64, 4 waves (64x32 each),
// 24KB LDS -> 2+ blocks/CU (was 128x128, 1/CU). 1D grid 512 with XCD
// m-octet swizzle (A-panel 1MB + B 2MB per XCD fits L2).
// xo f32 = C + hres.
// ---------------------------------------------------------------------------
__global__ __launch_bounds__(256)
void mm128_kernel(const unsigned short* __restrict__ Abf,
                  const unsigned short* __restrict__ Bbf,
                  const float* __restrict__ hres,
                  float* __restrict__ xo)
{
    __shared__ unsigned short As[128 * 64];   // 16KB
    __shared__ unsigned short Bs[64 * 64];    // 8KB

    const int bid = blockIdx.x;
    const int o = bid & 7, j = bid >> 3;
    const int m0 = (o * 4 + (j & 3)) * 128;
    const int n0 = (j >> 2) * 64;

    const int t  = threadIdx.x;
    const int w  = t >> 6;
    const int l  = t & 63;
    const int lj = l & 15;
    const int lg = l >> 4;
    const int wr = w >> 1, wc = w & 1;
    const int rsub = l >> 3;
    const int csw  = ((l & 7) ^ rsub) * 16;

    v4f acc[4][2] = {};

    for (int s = 0; s < 16; ++s) {
        const int k0b = s * 128;
        __syncthreads();
        #pragma unroll
        for (int u = 0; u < 4; ++u) {
            int ra = w * 32 + u * 8;
            gll16((const char*)Abf + (size_t)(m0 + ra + rsub) * 2048 + k0b + csw,
                  (char*)As + ra * 128);
        }
        #pragma unroll
        for (int u = 0; u < 2; ++u) {
            int ra = w * 16 + u * 8;
            gll16((const char*)Bbf + (size_t)(n0 + ra + rsub) * 2048 + k0b + csw,
                  (char*)Bs + ra * 128);
        }
        __syncthreads();
        #pragma unroll
        for (int ks = 0; ks < 2; ++ks) {
            bf16x8 af[4], bfr[2];
            #pragma unroll
            for (int m = 0; m < 4; ++m) {
                int row = wr * 64 + m * 16 + lj;
                int c = ks * 4 + lg;
                af[m] = *(const bf16x8*)((const char*)As + row * 128 +
                                         ((c ^ (row & 7)) * 16));
            }
            #pragma unroll
            for (int nn = 0; nn < 2; ++nn) {
                int row = wc * 32 + nn * 16 + lj;
                int c = ks * 4 + lg;
                bfr[nn] = *(const bf16x8*)((const char*)Bs + row * 128 +
                                           ((c ^ (row & 7)) * 16));
            }
            __builtin_amdgcn_s_setprio(1);
            #pragma unroll
            for (int m = 0; m < 4; ++m)
                #pragma unroll
                for (int nn = 0; nn < 2; ++nn)
                    acc[m][nn] = __builtin_amdgcn_mfma_f32_16x16x32_bf16(
                                     af[m], bfr[nn], acc[m][nn], 0, 0, 0);
            __builtin_amdgcn_s_setprio(0);
        }
    }

    #pragma unroll
    for (int m = 0; m < 4; ++m) {
        #pragma unroll
        for (int rr = 0; rr < 4; ++rr) {
            int row = m0 + wr * 64 + m * 16 + 4 * lg + rr;
            #pragma unroll
            for (int nn = 0; nn < 2; ++nn) {
                int col = n0 + wc * 32 + nn * 16 + lj;
                xo[(size_t)row * 1024 + col] =
                    acc[m][nn][rr] + hres[(size_t)row * 1024 + col];
            }
        }
    }
}

// ---------------------------------------------------------------------------
// Merged DPFP features + V transpose (one launch).
// blocks [0,1536): dpfp; [1536,2048): vtrans.
// ---------------------------------------------------------------------------
__device__ __forceinline__ float gld(const unsigned short* gr, int idx) {
    return __builtin_bit_cast(float, ((unsigned int)gr[idx]) << 16);
}

template<int FBASE>
__device__ __forceinline__ void dpfp_half8(const unsigned short* __restrict__ gr,
                                           unsigned char* __restrict__ drow)
{
    #pragma unroll
    for (int c = 0; c < 12; ++c) {
        unsigned int w4[4];
        #pragma unroll
        for (int q4 = 0; q4 < 4; ++q4) {
            float p[4];
            #pragma unroll
            for (int e = 0; e < 4; ++e) {
                const int f  = FBASE + c * 16 + q4 * 4 + e;
                const int r  = (f >> 7) + 1;
                const int tt = f & 127;
                const int uu = (tt - r) & 127;
                p[e] = gld(gr, tt) * gld(gr, uu);
            }
            int v = __builtin_amdgcn_cvt_pk_fp8_f32(p[0], p[1], 0, false);
            v     = __builtin_amdgcn_cvt_pk_fp8_f32(p[2], p[3], v, true);
            w4[q4] = (unsigned int)v;
        }
        u32x4 st = {w4[0], w4[1], w4[2], w4[3]};
        *(u32x4*)(drow + c * 1024) = st;
    }
}

__global__ __launch_bounds__(256)
void feat_kernel(const unsigned short* __restrict__ qraw,
                 const unsigned short* __restrict__ kraw,
                 const unsigned short* __restrict__ vraw,
                 unsigned char* __restrict__ qf, unsigned char* __restrict__ kf,
                 unsigned short* __restrict__ vt)
{
    __shared__ __align__(16) char smem[36864];
    const int t   = threadIdx.x;
    const int blk = blockIdx.x;

    if (blk >= 1536) {
        unsigned short (*S)[72] = (unsigned short(*)[72])smem;
        int v = blk - 1536;
        int jc = v & 3, hh = (v >> 2) & 15, b = v >> 6;
        const unsigned short* src = vraw + (size_t)((jc * 256 + t) * 8 + b) * 1024 + hh * 64;
        #pragma unroll
        for (int c = 0; c < 8; ++c)
            *(u32x4*)&S[t][c * 8] = *(const u32x4*)(src + c * 8);
        __syncthreads();
        const int d = t >> 2, qq = t & 3;
        unsigned short* dst = vt + ((size_t)(b * NH + hh) * HD + d) * KLEN + jc * 256 + qq * 64;
        #pragma unroll
        for (int c8 = 0; c8 < 8; ++c8) {
            u16x8 o;
            #pragma unroll
            for (int e = 0; e < 8; ++e) o[e] = S[qq * 64 + c8 * 8 + e][d];
            *(u16x8*)(dst + c8 * 8) = o;
        }
        return;
    }

    unsigned short* G = (unsigned short*)smem;   // [128][138]
    const unsigned short* src; unsigned char* dst; int b, hh, seq0;
    if (blk < 512) {
        int bh = blk >> 2, ig = blk & 3;
        b = bh >> 4; hh = bh & 15; seq0 = ig * 128;
        src = qraw; dst = qf + (size_t)bh * 196608;
    } else {
        int blk2 = blk - 512;
        int bh = blk2 >> 3, jg = blk2 & 7;
        b = bh >> 4; hh = bh & 15; seq0 = jg * 128;
        src = kraw; dst = kf + (size_t)bh * 393216;
    }

    #pragma unroll
    for (int p = 0; p < 4; ++p) {
        int u   = p * 256 + t;
        int row = u >> 3;
        int c0  = (u & 7) * 8;
        u32x4 x = *(const u32x4*)(src + ((size_t)(seq0 + row) * 8 + b) * 1024 +
                                  hh * 64 + c0);
        char* gbase = (char*)G + row * 276 + c0 * 2;
        #pragma unroll
        for (int k = 0; k < 4; ++k) {
            unsigned int xk = x[k];
            float x0 = __builtin_bit_cast(float, xk << 16);
            float x1 = __builtin_bit_cast(float, xk & 0xffff0000u);
            float a0 = fmaxf(x0, 0.f), a1 = fmaxf(x1, 0.f);
            float b0 = fmaxf(-x0, 0.f), b1 = fmaxf(-x1, 0.f);
            unsigned int lo, hig;
            asm("v_cvt_pk_bf16_f32 %0, %1, %2" : "=v"(lo) : "v"(a0), "v"(a1));
            asm("v_cvt_pk_bf16_f32 %0, %1, %2" : "=v"(hig) : "v"(b0), "v"(b1));
            *(unsigned int*)(gbase + k * 4)       = lo;
            *(unsigned int*)(gbase + 128 + k * 4) = hig;
        }
    }
    __syncthreads();

    const int w    = t >> 6;
    const int l    = t & 63;
    const int rowc = (w >> 1) * 64 + l;
    const int hs   = w & 1;
    const unsigned short* gr = G + rowc * 138;
    const int seq = seq0 + rowc;
    unsigned char* drow = dst + (size_t)(seq >> 6) * 24576 + (seq & 63) * 16 +
                          hs * 12288;
    if (hs == 0) dpfp_half8<0>(gr, drow);
    else         dpfp_half8<192>(gr, drow);
}

// ---------------------------------------------------------------------------
// MFMA attention: fp8 QK^T (swapped), in-reg P via cvt_pk + permlane32_swap,
// bf16 PV. KVBLK=64, 4 waves x 32 i. Complementary it-pairing: block k and
// k+256 (same CU under in-order dispatch) get it and 3-it, so per-CU work
// is constant 26 tile-steps.
// ---------------------------------------------------------------------------
__global__ __launch_bounds__(256, 2)
void attn_mfma_kernel(const unsigned char* __restrict__ qf,
                      const unsigned char* __restrict__ kf,
                      const unsigned short* __restrict__ vt,
                      unsigned short* __restrict__ avec)
{
    __shared__ unsigned char Ks[64 * 384];    // 24KB fp8: [cell24][row64][16B]
    __shared__ unsigned short Vs[64 * 64];    // 8KB bf16: rows(d) 128B, swizzled
    __shared__ float Ds[4][32];

    const int t  = threadIdx.x;
    const int w  = t >> 6;
    const int l  = t & 63;
    const int li = l & 31;
    const int hi = l >> 5;

    const int bid = blockIdx.x;
    const int it  = (((bid >> 3) & 3)) ^ ((((bid >> 8) & 1)) * 3);
    const int P   = ((bid >> 5) << 3) + (bid & 7);
    const int n   = P & 15;
    const int b   = P >> 4;

    const unsigned char* qpan = qf + (size_t)P * 196608;
    const unsigned char* kpan = kf + (size_t)P * 393216;
    const char* vpan = (const char*)(vt + (size_t)P * HD * KLEN);

    int voff[2];
    #pragma unroll
    for (int uu = 0; uu < 2; ++uu) {
        int s  = (w * 2 + uu) * 64 + l;
        int d  = s >> 3;
        int cl = s & 7;
        int cg = cl ^ (d & 7);
        voff[uu] = d * (KLEN * 2) + cg * 16;
    }

    long qfr[24];
    {
        const unsigned char* qb = qpan + (size_t)(it * 2 + (w >> 1)) * 24576 +
                                  ((w & 1) * 32 + li) * 16 + hi * 8;
        #pragma unroll
        for (int ks = 0; ks < 24; ++ks)
            qfr[ks] = *(const long*)(qb + ks * 1024);
    }

    f32x16 num[2] = {};
    float den_acc = 0.f;

    const int ig         = it * 128 + w * 32 + li;
    const int my_jt_end  = 2 * it + 8 + (w >> 1);
    const int jt_blk_end = 2 * it + 9;

    for (int jt = 0; jt <= jt_blk_end; ++jt) {
        __syncthreads();
        const unsigned char* ktile = kpan + (size_t)jt * 24576;
        #pragma unroll
        for (int u = 0; u < 6; ++u)
            gll16(ktile + (w * 6 + u) * 1024 + l * 16, Ks + (w * 6 + u) * 1024);
        const char* vtile = vpan + jt * 128;
        #pragma unroll
        for (int uu = 0; uu < 2; ++uu)
            gll16(vtile + voff[uu], (char*)Vs + (w * 2 + uu) * 1024);
        __syncthreads();

        if (jt > my_jt_end) continue;

        f32x16 sacc0 = {};
        f32x16 sacc1 = {};
        __builtin_amdgcn_s_setprio(1);
        #pragma unroll
        for (int ks = 0; ks < 24; ++ks) {
            long k0 = *(const long*)(Ks + ks * 1024 + li * 16 + hi * 8);
            long k1 = *(const long*)(Ks + ks * 1024 + (32 + li) * 16 + hi * 8);
            sacc0 = __builtin_amdgcn_mfma_f32_32x32x16_fp8_fp8(k0, qfr[ks], sacc0, 0, 0, 0);
            sacc1 = __builtin_amdgcn_mfma_f32_32x32x16_fp8_fp8(k1, qfr[ks], sacc1, 0, 0, 0);
        }
        __builtin_amdgcn_s_setprio(0);

        if (jt == my_jt_end) {
            const int joff = jt * 64 - MLEN + 4 * hi;
            #pragma unroll
            for (int reg = 0; reg < 16; ++reg) {
                int jr = (reg & 3) + 8 * (reg >> 2);
                if (joff + jr > ig)      sacc0[reg] = 0.f;
                if (joff + 32 + jr > ig) sacc1[reg] = 0.f;
            }
        }
        {
            float dpart = 0.f;
            #pragma unroll
            for (int reg = 0; reg < 16; ++reg) dpart += sacc0[reg] + sacc1[reg];
            den_acc += dpart + __shfl_xor(dpart, 32);
        }

        #pragma unroll
        for (int jf = 0; jf < 2; ++jf) {
            const f32x16 sc = jf ? sacc1 : sacc0;
            unsigned int c01, c23, c45, c67, c89, cab, ccd, cef;
            asm("v_cvt_pk_bf16_f32 %0, %1, %2" : "=v"(c01) : "v"(sc[0]),  "v"(sc[1]));
            asm("v_cvt_pk_bf16_f32 %0, %1, %2" : "=v"(c23) : "v"(sc[2]),  "v"(sc[3]));
            asm("v_cvt_pk_bf16_f32 %0, %1, %2" : "=v"(c45) : "v"(sc[4]),  "v"(sc[5]));
            asm("v_cvt_pk_bf16_f32 %0, %1, %2" : "=v"(c67) : "v"(sc[6]),  "v"(sc[7]));
            asm("v_cvt_pk_bf16_f32 %0, %1, %2" : "=v"(c89) : "v"(sc[8]),  "v"(sc[9]));
            asm("v_cvt_pk_bf16_f32 %0, %1, %2" : "=v"(cab) : "v"(sc[10]), "v"(sc[11]));
            asm("v_cvt_pk_bf16_f32 %0, %1, %2" : "=v"(ccd) : "v"(sc[12]), "v"(sc[13]));
            asm("v_cvt_pk_bf16_f32 %0, %1, %2" : "=v"(cef) : "v"(sc[14]), "v"(sc[15]));
            u32x2 r0 = __builtin_amdgcn_permlane32_swap(c01, c45, false, false);
            u32x2 r1 = __builtin_amdgcn_permlane32_swap(c23, c67, false, false);
            u32x2 r2 = __builtin_amdgcn_permlane32_swap(c89, ccd, false, false);
            u32x2 r3 = __builtin_amdgcn_permlane32_swap(cab, cef, false, false);
            u32x4 pw0 = {r0.x, r1.x, r0.y, r1.y};
            u32x4 pw1 = {r2.x, r3.x, r2.y, r3.y};
            bf16x8 pa0 = __builtin_bit_cast(bf16x8, pw0);
            bf16x8 pa1 = __builtin_bit_cast(bf16x8, pw1);
            __builtin_amdgcn_s_setprio(1);
            #pragma unroll
            for (int dd = 0; dd < 2; ++dd) {
                int d = dd * 32 + li;
                {
                    int cs = (jf * 4 + hi) ^ (d & 7);
                    bf16x8 vb = *(const bf16x8*)((const char*)Vs + d * 128 + cs * 16);
                    num[dd] = __builtin_amdgcn_mfma_f32_32x32x16_bf16(pa0, vb, num[dd], 0, 0, 0);
                }
                {
                    int cs = (jf * 4 + 2 + hi) ^ (d & 7);
                    bf16x8 vb = *(const bf16x8*)((const char*)Vs + d * 128 + cs * 16);
                    num[dd] = __builtin_amdgcn_mfma_f32_32x32x16_bf16(pa1, vb, num[dd], 0, 0, 0);
                }
            }
            __builtin_amdgcn_s_setprio(0);
        }
    }

    if (l < 32) Ds[w][l] = den_acc;
    #pragma unroll
    for (int reg = 0; reg < 16; ++reg) {
        int i_loc = (reg & 3) + 8 * (reg >> 2) + 4 * hi;
        float dv = Ds[w][i_loc];
        float minv = ATT_SCALE / (dv * ATT_SCALE + EPSV);
        int ig2 = it * 128 + w * 32 + i_loc;
        unsigned short* orow = avec + ((size_t)ig2 * BB + b) * DMODEL + n * HD;
        orow[li]      = f2bf(num[0][reg] * minv);
        orow[32 + li] = f2bf(num[1][reg] * minv);
    }
}

// ---------------------------------------------------------------------------
// Row LayerNorm over DM=1024.
// ---------------------------------------------------------------------------
__global__ __launch_bounds__(256)
void ln_kernel(const float* __restrict__ x, const float* __restrict__ gamma,
               const float* __restrict__ beta, float* __restrict__ out)
{
    const int row = blockIdx.x;
    const int t = threadIdx.x;
    const float* xr = x + (size_t)row * DMODEL;
    v4f xv = *(const v4f*)(xr + (t << 2));
    float s1 = xv[0] + xv[1] + xv[2] + xv[3];
    float s2 = xv[0]*xv[0] + xv[1]*xv[1] + xv[2]*xv[2] + xv[3]*xv[3];
    #pragma unroll
    for (int off = 32; off > 0; off >>= 1) {
        s1 += __shfl_down(s1, off);
        s2 += __shfl_down(s2, off);
    }
    __shared__ float red[2][4];
    __shared__ float mv[2];
    const int wave = t >> 6;
    if ((t & 63) == 0) { red[0][wave] = s1; red[1][wave] = s2; }
    __syncthreads();
    if (t == 0) {
        float a = red[0][0] + red[0][1] + red[0][2] + red[0][3];
        float q = red[1][0] + red[1][1] + red[1][2] + red[1][3];
        float mu  = a * (1.f / DMODEL);
        float var = q * (1.f / DMODEL) - mu * mu;
        mv[0] = mu;
        mv[1] = rsqrtf(var + EPSV);
    }
    __syncthreads();
    float mu = mv[0], rs = mv[1];
    v4f gv = *(const v4f*)(gamma + (t << 2));
    v4f bv = *(const v4f*)(beta + (t << 2));
    v4f o;
    #pragma unroll
    for (int e = 0; e < 4; ++e) o[e] = (xv[e] - mu) * rs * gv[e] + bv[e];
    *(v4f*)(out + (size_t)row * DMODEL + (t << 2)) = o;
}

extern "C" void kernel_launch(void* const* d_in, const int* in_sizes, int n_in,
                              void* d_out, int out_size, void* d_ws, size_t ws_size,
                              hipStream_t stream)
{
    const float* h     = (const float*)d_in[0];
    const float* mems  = (const float*)d_in[1];
    const float* Wq    = (const float*)d_in[2];
    const float* Wkv   = (const float*)d_in[3];
    const float* Wo    = (const float*)d_in[4];
    const float* gamma = (const float*)d_in[5];
    const float* beta  = (const float*)d_in[6];
    // d_in[7] = attn_mask: causal structure computed analytically, ignored.

    char* ws = (char*)d_ws;
    unsigned char* qf    = (unsigned char*)(ws);              // 25.17M fp8 feats
    unsigned char* kf    = (unsigned char*)(ws + 25165824);   // 50.33M fp8 feats
    unsigned char* c8    = (unsigned char*)(ws + 75497472);   // 8.39M fp8
    unsigned char* wkv8  = (unsigned char*)(ws + 83886080);   // 2.10M fp8
    unsigned char* wq8   = (unsigned char*)(ws + 85983232);   // 1.05M fp8
    unsigned short* vt   = (unsigned short*)(ws + 92274688);  // 16.78M bf16 (own region)
    unsigned short* kraw = (unsigned short*)(ws + 150994944); // 16.78M bf16
    unsigned short* vraw = (unsigned short*)(ws + 167772160); // 16.78M
    unsigned short* qraw = (unsigned short*)(ws + 184549376); // 8.39M
    unsigned short* avec = qraw;                              // overlay after feat
    float* xws = (float*)(ws);                                // overlay qf after attn

    unsigned short* wob = (unsigned short*)d_out;             // bf16 Wo in d_out

    cvt_kernel<<<6656, 256, 0, stream>>>(h, mems, Wkv, Wq, Wo, c8, wkv8, wq8, wob);
    mmfp8_kernel<<<2560, 256, 0, stream>>>(c8, wkv8, wq8, kraw, vraw, qraw);
    feat_kernel<<<2048, 256, 0, stream>>>(qraw, kraw, vraw, qf, kf, vt);
    attn_mfma_kernel<<<512, 256, 0, stream>>>(qf, kf, vt, avec);
    mm128_kernel<<<512, 256, 0, stream>>>(avec, wob, h, xws);
    ln_kernel<<<4096, 256, 0, stream>>>(xws, gamma, beta, (float*)d_out);
}